// Round 2
// baseline (113.341 us; speedup 1.0000x reference)
//
#include <hip/hip_runtime.h>

#define S_ROWS 2048
#define RO_ROWS 8192
#define HEADS 8
#define HDIM 32
#define ROWLEN 256   // HEADS * HDIM

typedef __attribute__((ext_vector_type(8))) short bf16x8;
typedef __attribute__((ext_vector_type(4))) float f32x4;
typedef __attribute__((ext_vector_type(4))) short s16x4;

__device__ __forceinline__ short f32_to_bf16_rne(float f) {
    union { float f; unsigned u; } v; v.f = f;
    return (short)((v.u + 0x7fffu + ((v.u >> 16) & 1u)) >> 16);
}

// Normalize every 32-element head vector of both inputs, emit bf16.
// float4 per thread: one head vector = 8 consecutive threads (aligned 8-lane
// group within the wave), so shfl_xor 1/2/4 reduces the squared norm.
__global__ __launch_bounds__(256) void mhd_normalize(const float* __restrict__ s,
                                                     const float* __restrict__ ro,
                                                     short* __restrict__ outN) {
    const int idx = blockIdx.x * 256 + threadIdx.x;       // vec4 index
    const int S_TOT4 = S_ROWS * ROWLEN / 4;
    f32x4 x = (idx < S_TOT4) ? ((const f32x4*)s)[idx]
                             : ((const f32x4*)ro)[idx - S_TOT4];
    float ss = x[0] * x[0] + x[1] * x[1] + x[2] * x[2] + x[3] * x[3];
    ss += __shfl_xor(ss, 1);
    ss += __shfl_xor(ss, 2);
    ss += __shfl_xor(ss, 4);
    const float inv = rsqrtf(ss);
    s16x4 r;
    r[0] = f32_to_bf16_rne(x[0] * inv);
    r[1] = f32_to_bf16_rne(x[1] * inv);
    r[2] = f32_to_bf16_rne(x[2] * inv);
    r[3] = f32_to_bf16_rne(x[3] * inv);
    ((s16x4*)outN)[idx] = r;
}

// Each wave computes a 64x64 output tile: per head, 4 A-frags x 4 B-frags,
// 16 MFMAs (16x16x32, K=32 == HDIM, C=0), elementwise max into running max.
// Operand order is mfma(b, a): D col=lane&15 indexes s-rows (output rows),
// D reg axis row=(lane>>4)*4+q indexes ro-rows (output cols) -> each lane
// holds 4 consecutive output columns => float4 stores.
// Head loop NOT unrolled: keeps frag live range to one head (no VGPR spill).
__global__ __launch_bounds__(256) void mhd_dist(const short* __restrict__ sN,
                                                const short* __restrict__ roN,
                                                float* __restrict__ out) {
    const int lane = threadIdx.x & 63;
    const int wave = threadIdx.x >> 6;   // 4 waves: 2x2 of 64x64 tiles
    const int wr = wave >> 1;
    const int wc = wave & 1;
    const int tile_r = blockIdx.x >> 6;  // 16 row tiles of 128
    const int tile_c = blockIdx.x & 63;  // 64 col tiles of 128
    const int row0 = tile_r * 128 + wr * 64;
    const int col0 = tile_c * 128 + wc * 64;
    const int l15 = lane & 15;
    const int kg = lane >> 4;

    f32x4 runmax[4][4];
#pragma unroll
    for (int i = 0; i < 4; ++i)
#pragma unroll
        for (int j = 0; j < 4; ++j)
            runmax[i][j] = (f32x4){-3.0e38f, -3.0e38f, -3.0e38f, -3.0e38f};

    const size_t aBase = (size_t)(row0 + l15) * ROWLEN + kg * 8;
    const size_t bBase = (size_t)(col0 + l15) * ROWLEN + kg * 8;

#pragma unroll 1
    for (int h = 0; h < HEADS; ++h) {
        const size_t hoff = (size_t)h * HDIM;
        bf16x8 a[4], b[4];
#pragma unroll
        for (int i = 0; i < 4; ++i) {
            a[i] = *(const bf16x8*)(sN + aBase + (size_t)i * 16 * ROWLEN + hoff);
            b[i] = *(const bf16x8*)(roN + bBase + (size_t)i * 16 * ROWLEN + hoff);
        }
#pragma unroll
        for (int i = 0; i < 4; ++i)
#pragma unroll
            for (int j = 0; j < 4; ++j) {
                f32x4 acc = {0.f, 0.f, 0.f, 0.f};
                acc = __builtin_amdgcn_mfma_f32_16x16x32_bf16(b[j], a[i], acc, 0, 0, 0);
#pragma unroll
                for (int q = 0; q < 4; ++q)
                    runmax[i][j][q] = fmaxf(runmax[i][j][q], acc[q]);
            }
    }

    // lane holds: rows row0+i*16+l15, cols col0+j*16+kg*4 .. +3 -> float4
#pragma unroll
    for (int i = 0; i < 4; ++i) {
        float* rowp = out + (size_t)(row0 + i * 16 + l15) * RO_ROWS + col0 + kg * 4;
#pragma unroll
        for (int j = 0; j < 4; ++j)
            *(f32x4*)(rowp + j * 16) = runmax[i][j];
    }
}

extern "C" void kernel_launch(void* const* d_in, const int* in_sizes, int n_in,
                              void* d_out, int out_size, void* d_ws, size_t ws_size,
                              hipStream_t stream) {
    const float* batch_s  = (const float*)d_in[0];
    const float* batch_ro = (const float*)d_in[1];
    float* out = (float*)d_out;

    short* sN  = (short*)d_ws;                 // 2048*256 bf16 = 1 MiB
    short* roN = sN + (size_t)S_ROWS * ROWLEN; // 8192*256 bf16 = 4 MiB

    const int totalV4 = (S_ROWS + RO_ROWS) * ROWLEN / 4;   // 655360 (exact x256)
    mhd_normalize<<<totalV4 / 256, 256, 0, stream>>>(batch_s, batch_ro, sN);

    mhd_dist<<<(S_ROWS / 128) * (RO_ROWS / 128), 256, 0, stream>>>(sN, roN, out);
}